// Round 4
// baseline (7417.119 us; speedup 1.0000x reference)
//
#include <hip/hip_runtime.h>

#define B_ 1024
#define T_ 100
#define F_ 300
#define FP_ 320
#define U_ 512
#define G4_ 2048
#define C_ 10
#define EPS_ 1e-3f

typedef _Float16 f16x8 __attribute__((ext_vector_type(8)));
typedef float f32x4 __attribute__((ext_vector_type(4)));

typedef __attribute__((address_space(1))) const void* gcptr_t;
typedef __attribute__((address_space(3))) void* lptr_t;

__device__ __forceinline__ void async_ld16(_Float16* lds, const _Float16* g) {
  __builtin_amdgcn_global_load_lds((gcptr_t)g, (lptr_t)lds, 16, 0, 0);
}

// ---------------- prologue kernels ----------------

// x (B,T,F) fp32 -> x_hi/x_lo [T][B][FP_] fp16 split, zero-padded F..FP_
__global__ __launch_bounds__(256) void cast_x_kernel(const float* __restrict__ x,
                                                     _Float16* __restrict__ xhi,
                                                     _Float16* __restrict__ xlo) {
  size_t idx = (size_t)blockIdx.x * 256 + threadIdx.x;
  int f = (int)(idx % FP_);
  size_t bt = idx / FP_;
  int b = (int)(bt % B_);
  int t = (int)(bt / B_);
  float v = 0.f;
  if (f < F_) v = x[((size_t)b * T_ + t) * F_ + f];
  _Float16 h = (_Float16)v;
  xhi[idx] = h;
  xlo[idx] = (_Float16)(v - (float)h);
}

// W [K][N] fp32 -> Wt_hi/Wt_lo [N][Kp] fp16 split (transposed, zero-padded K..Kp)
__global__ __launch_bounds__(256) void cast_w_kernel(const float* __restrict__ W,
                                                     _Float16* __restrict__ Whi,
                                                     _Float16* __restrict__ Wlo,
                                                     int K, int N, int Kp) {
  __shared__ float tile[32][33];
  int n0 = blockIdx.x * 32, k0 = blockIdx.y * 32;
  int tx = threadIdx.x & 31, ty = threadIdx.x >> 5;
#pragma unroll
  for (int r = 0; r < 32; r += 8) {
    int k = k0 + ty + r;
    tile[ty + r][tx] = (k < K) ? W[(size_t)k * N + n0 + tx] : 0.f;
  }
  __syncthreads();
#pragma unroll
  for (int r = 0; r < 32; r += 8) {
    int n = n0 + ty + r, kk = k0 + tx;
    if (kk < Kp) {
      float v = tile[tx][ty + r];
      _Float16 h = (_Float16)v;
      Whi[(size_t)n * Kp + kk] = h;
      Wlo[(size_t)n * Kp + kk] = (_Float16)(v - (float)h);
    }
  }
}

// ---------------- GEMM: G = A (MxK) * Bt^T (Bt is [N][K]) ----------------
// Split-fp16, one precision segment per blockIdx.z slice:
//   seg 0: A_hi@B_hi -> Ghi (fp32)   seg 1: A_lo@B_hi -> Gl1 (fp16)
//   seg 2: A_hi@B_lo -> Gl2 (fp16)
// Block tile 64(M)x128(N), BK=64, 128 threads = 2 waves, wave tile 64x64.
// Staging: global_load_lds 16B, XOR-swizzled chunk layout (conflict-free b128 reads).
// blockIdx.z = op*3 + seg, up to 3 independent GEMM ops.
struct GemmOp {
  const _Float16* A;
  const _Float16* Bt;
  float* Ghi;
  _Float16* Gl1;
  _Float16* Gl2;
  int lda;
  int K;
  size_t aLo;
};

__global__ __launch_bounds__(128) void gemm3_kernel(GemmOp o0, GemmOp o1, GemmOp o2) {
  unsigned zz = blockIdx.z;
  unsigned opIdx = zz / 3u, seg = zz % 3u;
  GemmOp op = (opIdx == 0) ? o0 : ((opIdx == 1) ? o1 : o2);
  const int K = op.K, lda = op.lda;
  const _Float16* Ap = op.A + ((seg == 1) ? op.aLo : 0);
  const _Float16* Bp = op.Bt + ((seg == 2) ? (size_t)G4_ * K : 0);

  __shared__ __align__(16) _Float16 as[64][64];   // 8 KB
  __shared__ __align__(16) _Float16 bs[128][64];  // 16 KB

  const int tid = threadIdx.x;
  const int w = tid >> 6;  // 0..1
  const int lane = tid & 63;
  const int mBase = blockIdx.y * 64, nBase = blockIdx.x * 128;
  const int wn = w << 6;

  f32x4 acc[4][4];
#pragma unroll
  for (int mt = 0; mt < 4; mt++)
#pragma unroll
    for (int nt = 0; nt < 4; nt++) acc[mt][nt] = (f32x4){0.f, 0.f, 0.f, 0.f};

#pragma unroll 1
  for (int k0 = 0; k0 < K; k0 += 64) {
    // stage A: 8 issues total (4 per wave), each 64 lanes x 16B
#pragma unroll
    for (int j = 0; j < 4; j++) {
      int i = (w << 2) + j;
      int idx = (i << 6) + lane;
      int row = idx >> 3;
      int cl = ((idx & 7) ^ (row & 7)) << 3;
      async_ld16(&as[0][0] + (i << 9),
                 Ap + (size_t)(mBase + row) * lda + k0 + cl);
    }
    // stage B: 16 issues total (8 per wave)
#pragma unroll
    for (int j = 0; j < 8; j++) {
      int i = (w << 3) + j;
      int idx = (i << 6) + lane;
      int row = idx >> 3;
      int cl = ((idx & 7) ^ (row & 7)) << 3;
      async_ld16(&bs[0][0] + (i << 9),
                 Bp + (size_t)(nBase + row) * K + k0 + cl);
    }
    __syncthreads();
#pragma unroll
    for (int q = 0; q < 2; q++) {
      f16x8 af[4], bf[4];
#pragma unroll
      for (int mt = 0; mt < 4; mt++) {
        int row = (mt << 4) + (lane & 15);
        int p = ((q << 2) + (lane >> 4)) ^ (row & 7);
        af[mt] = *(const f16x8*)&as[row][p << 3];
      }
#pragma unroll
      for (int nt = 0; nt < 4; nt++) {
        int row = wn + (nt << 4) + (lane & 15);
        int p = ((q << 2) + (lane >> 4)) ^ (row & 7);
        bf[nt] = *(const f16x8*)&bs[row][p << 3];
      }
#pragma unroll
      for (int mt = 0; mt < 4; mt++)
#pragma unroll
        for (int nt = 0; nt < 4; nt++)
          acc[mt][nt] = __builtin_amdgcn_mfma_f32_16x16x32_f16(af[mt], bf[nt], acc[mt][nt], 0, 0, 0);
    }
    __syncthreads();
  }
  // C/D layout: col = lane&15, row = (lane>>4)*4 + reg
  int q = lane >> 4, c = lane & 15;
  if (seg == 0) {
    float* G = op.Ghi;
#pragma unroll
    for (int mt = 0; mt < 4; mt++)
#pragma unroll
      for (int nt = 0; nt < 4; nt++)
#pragma unroll
        for (int r = 0; r < 4; r++) {
          int row = mBase + (mt << 4) + (q << 2) + r;
          int col = nBase + wn + (nt << 4) + c;
          G[(size_t)row * G4_ + col] = acc[mt][nt][r];
        }
  } else {
    _Float16* G = (seg == 1) ? op.Gl1 : op.Gl2;
#pragma unroll
    for (int mt = 0; mt < 4; mt++)
#pragma unroll
      for (int nt = 0; nt < 4; nt++)
#pragma unroll
        for (int r = 0; r < 4; r++) {
          int row = mBase + (mt << 4) + (q << 2) + r;
          int col = nBase + wn + (nt << 4) + c;
          G[(size_t)row * G4_ + col] = (_Float16)acc[mt][nt][r];
        }
  }
}

// ---------------- cell (LN + gates + c-LN + mask) ----------------

__device__ __forceinline__ void block_reduce(float* v, int n, float* sred, int tid) {
  int lane = tid & 63, w = tid >> 6;
  for (int off = 32; off > 0; off >>= 1)
    for (int i = 0; i < n; i++) v[i] += __shfl_down(v[i], off, 64);
  if (lane == 0)
    for (int i = 0; i < n; i++) sred[w * 4 + i] = v[i];
  __syncthreads();
  if (tid == 0)
    for (int i = 0; i < n; i++) sred[16 + i] = sred[i] + sred[4 + i] + sred[8 + i] + sred[12 + i];
  __syncthreads();
  for (int i = 0; i < n; i++) v[i] = sred[16 + i];
}

__device__ __forceinline__ float sigm(float x) { return 1.f / (1.f + expf(-x)); }

// h state carried as fp16 (hi,lo) pair: hHi = hP, hLo = hP + B*U. c state fp32.
__global__ __launch_bounds__(256) void cell_kernel(
    const float* __restrict__ GxH, const _Float16* __restrict__ Gx1, const _Float16* __restrict__ Gx2,
    const float* __restrict__ GhH, const _Float16* __restrict__ Gh1, const _Float16* __restrict__ Gh2,
    const float* __restrict__ bias, const float* __restrict__ kg, const float* __restrict__ kb,
    const float* __restrict__ rg, const float* __restrict__ rb,
    const float* __restrict__ sg, const float* __restrict__ sb,
    float* __restrict__ cS, _Float16* __restrict__ hP,
    _Float16* __restrict__ hnP, float* __restrict__ outb,
    const int* __restrict__ mask, int step) {
  int b = blockIdx.x, tid = threadIdx.x;
  __shared__ float sred[20];
  size_t gbase = (size_t)b * G4_;
  float vx[8], vh[8];
  float s[4] = {0.f, 0.f, 0.f, 0.f};
#pragma unroll
  for (int i = 0; i < 8; i++) {
    int col = tid + (i << 8);
    float a = GxH[gbase + col] + (float)Gx1[gbase + col] + (float)Gx2[gbase + col];
    float d = GhH[gbase + col] + (float)Gh1[gbase + col] + (float)Gh2[gbase + col];
    vx[i] = a;
    vh[i] = d;
    s[0] += a;
    s[1] += a * a;
    s[2] += d;
    s[3] += d * d;
  }
  block_reduce(s, 4, sred, tid);
  const float inv = 1.f / 2048.f;
  float m1 = s[0] * inv, m2 = s[2] * inv;
  float rs1 = rsqrtf(fmaxf(s[1] * inv - m1 * m1, 0.f) + EPS_);
  float rs2 = rsqrtf(fmaxf(s[3] * inv - m2 * m2, 0.f) + EPS_);
  float z[8];
#pragma unroll
  for (int i = 0; i < 8; i++) {
    int col = tid + (i << 8);
    z[i] = (vx[i] - m1) * rs1 * kg[col] + kb[col] + (vh[i] - m2) * rs2 * rg[col] + rb[col] + bias[col];
  }
  // cols: i=0,1 -> i-gate (j0,j1); 2,3 -> f; 4,5 -> g; 6,7 -> o
  int j0 = tid, j1 = tid + 256;
  size_t base = (size_t)b * U_;
  _Float16* hHi = hP;
  _Float16* hLo = hP + (size_t)B_ * U_;
  float co0 = cS[base + j0], co1 = cS[base + j1];
  float cn0 = sigm(z[2]) * co0 + sigm(z[0]) * tanhf(z[4]);
  float cn1 = sigm(z[3]) * co1 + sigm(z[1]) * tanhf(z[5]);
  float t2[2] = {cn0 + cn1, cn0 * cn0 + cn1 * cn1};
  block_reduce(t2, 2, sred, tid);
  const float invU = 1.f / 512.f;
  float mc = t2[0] * invU;
  float rsc = rsqrtf(fmaxf(t2[1] * invU - mc * mc, 0.f) + EPS_);
  float cl0 = (cn0 - mc) * rsc * sg[j0] + sb[j0];
  float cl1 = (cn1 - mc) * rsc * sg[j1] + sb[j1];
  float hn0 = sigm(z[6]) * tanhf(cl0);
  float hn1 = sigm(z[7]) * tanhf(cl1);
  int mk = mask[(size_t)b * T_ + step];
  float ho0 = (float)hHi[base + j0] + (float)hLo[base + j0];
  float ho1 = (float)hHi[base + j1] + (float)hLo[base + j1];
  float hs0 = mk ? hn0 : ho0, hs1 = mk ? hn1 : ho1;
  _Float16 hh0 = (_Float16)hs0, hh1 = (_Float16)hs1;
  hHi[base + j0] = hh0;
  hLo[base + j0] = (_Float16)(hs0 - (float)hh0);
  hHi[base + j1] = hh1;
  hLo[base + j1] = (_Float16)(hs1 - (float)hh1);
  cS[base + j0] = mk ? cl0 : co0;
  cS[base + j1] = mk ? cl1 : co1;
  if (hnP) {  // layer-0: unmasked h_new feeds layer 1 (reference semantics)
    _Float16* nHi = hnP;
    _Float16* nLo = hnP + (size_t)B_ * U_;
    _Float16 n0 = (_Float16)hn0, n1 = (_Float16)hn1;
    nHi[base + j0] = n0;
    nLo[base + j0] = (_Float16)(hn0 - (float)n0);
    nHi[base + j1] = n1;
    nLo[base + j1] = (_Float16)(hn1 - (float)n1);
  }
  if (outb) {  // layer-1: out = mask ? hn : out_prev
    float oo0 = outb[base + j0], oo1 = outb[base + j1];
    outb[base + j0] = mk ? hn0 : oo0;
    outb[base + j1] = mk ? hn1 : oo1;
  }
}

// ---------------- final dense + softmax ----------------
__global__ __launch_bounds__(64) void dense_softmax_kernel(const float* __restrict__ outb,
                                                           const float* __restrict__ Wd,
                                                           const float* __restrict__ bd,
                                                           float* __restrict__ o) {
  int b = blockIdx.x, lane = threadIdx.x;
  __shared__ float sl[16];
  int col = lane & 15, kg = lane >> 4;
  float acc = 0.f;
  if (col < C_) {
    for (int k = kg; k < U_; k += 4) acc += outb[(size_t)b * U_ + k] * Wd[(size_t)k * C_ + col];
  }
  acc += __shfl_down(acc, 16, 64);
  acc += __shfl_down(acc, 32, 64);
  if (lane < C_) sl[lane] = acc + bd[lane];
  __syncthreads();
  if (lane < C_) {
    float mx = sl[0];
    for (int i = 1; i < C_; i++) mx = fmaxf(mx, sl[i]);
    float ssum = 0.f;
    for (int i = 0; i < C_; i++) ssum += expf(sl[i] - mx);
    o[(size_t)b * C_ + lane] = expf(sl[lane] - mx) / ssum;
  }
}

// ---------------- host ----------------

extern "C" void kernel_launch(void* const* d_in, const int* in_sizes, int n_in,
                              void* d_out, int out_size, void* d_ws, size_t ws_size,
                              hipStream_t stream) {
  const float* x = (const float*)d_in[0];
  const int* mask = (const int*)d_in[1];
  const float* W0 = (const float*)d_in[2];
  const float* R0 = (const float*)d_in[3];
  const float* b0 = (const float*)d_in[4];
  const float* kg0 = (const float*)d_in[5];
  const float* kb0 = (const float*)d_in[6];
  const float* rg0 = (const float*)d_in[7];
  const float* rb0 = (const float*)d_in[8];
  const float* sg0 = (const float*)d_in[9];
  const float* sb0 = (const float*)d_in[10];
  const float* W1 = (const float*)d_in[11];
  const float* R1 = (const float*)d_in[12];
  const float* b1 = (const float*)d_in[13];
  const float* kg1 = (const float*)d_in[14];
  const float* kb1 = (const float*)d_in[15];
  const float* rg1 = (const float*)d_in[16];
  const float* rb1 = (const float*)d_in[17];
  const float* sg1 = (const float*)d_in[18];
  const float* sb1 = (const float*)d_in[19];
  const float* Wd = (const float*)d_in[20];
  const float* bd = (const float*)d_in[21];
  float* out = (float*)d_out;

  char* w = (char*)d_ws;
  size_t o = 0;
  auto alloc = [&](size_t bytes) {
    size_t r = o;
    o += (bytes + 255) & ~(size_t)255;
    return r;
  };
  // zero region (contiguous, first)
  size_t o_c0s = alloc((size_t)B_ * U_ * 4);
  size_t o_c1s = alloc((size_t)B_ * U_ * 4);
  size_t o_outf = alloc((size_t)B_ * U_ * 4);
  size_t o_h0p = alloc((size_t)B_ * U_ * 2 * 2);  // hi + lo contiguous
  size_t o_h1p = alloc((size_t)B_ * U_ * 2 * 2);
  size_t zero_bytes = o;
  size_t o_hn0p = alloc((size_t)B_ * U_ * 2 * 2);
  size_t o_xh = alloc((size_t)T_ * B_ * FP_ * 2 * 2);  // hi + lo
  size_t o_W0t = alloc((size_t)G4_ * FP_ * 2 * 2);
  size_t o_R0t = alloc((size_t)G4_ * U_ * 2 * 2);
  size_t o_W1t = alloc((size_t)G4_ * U_ * 2 * 2);
  size_t o_R1t = alloc((size_t)G4_ * U_ * 2 * 2);
  // G buffers: hi fp32 + two lo fp16 per GEMM output
  size_t o_G0x = alloc((size_t)B_ * G4_ * 4);
  size_t o_G0xa = alloc((size_t)B_ * G4_ * 2);
  size_t o_G0xb = alloc((size_t)B_ * G4_ * 2);
  size_t o_G0h = alloc((size_t)B_ * G4_ * 4);
  size_t o_G0ha = alloc((size_t)B_ * G4_ * 2);
  size_t o_G0hb = alloc((size_t)B_ * G4_ * 2);
  size_t o_G1x = alloc((size_t)B_ * G4_ * 4);
  size_t o_G1xa = alloc((size_t)B_ * G4_ * 2);
  size_t o_G1xb = alloc((size_t)B_ * G4_ * 2);
  size_t o_G1h = alloc((size_t)B_ * G4_ * 4);
  size_t o_G1ha = alloc((size_t)B_ * G4_ * 2);
  size_t o_G1hb = alloc((size_t)B_ * G4_ * 2);
  (void)ws_size;

  float* c0s = (float*)(w + o_c0s);
  float* c1s = (float*)(w + o_c1s);
  float* outf = (float*)(w + o_outf);
  _Float16* h0p = (_Float16*)(w + o_h0p);
  _Float16* h1p = (_Float16*)(w + o_h1p);
  _Float16* hn0p = (_Float16*)(w + o_hn0p);
  _Float16* xh = (_Float16*)(w + o_xh);
  _Float16* W0t = (_Float16*)(w + o_W0t);
  _Float16* R0t = (_Float16*)(w + o_R0t);
  _Float16* W1t = (_Float16*)(w + o_W1t);
  _Float16* R1t = (_Float16*)(w + o_R1t);
  float* G0x = (float*)(w + o_G0x);
  _Float16* G0xa = (_Float16*)(w + o_G0xa);
  _Float16* G0xb = (_Float16*)(w + o_G0xb);
  float* G0h = (float*)(w + o_G0h);
  _Float16* G0ha = (_Float16*)(w + o_G0ha);
  _Float16* G0hb = (_Float16*)(w + o_G0hb);
  float* G1x = (float*)(w + o_G1x);
  _Float16* G1xa = (_Float16*)(w + o_G1xa);
  _Float16* G1xb = (_Float16*)(w + o_G1xb);
  float* G1h = (float*)(w + o_G1h);
  _Float16* G1ha = (_Float16*)(w + o_G1ha);
  _Float16* G1hb = (_Float16*)(w + o_G1hb);

  hipMemsetAsync(w, 0, zero_bytes, stream);

  {
    size_t total = (size_t)T_ * B_ * FP_;
    cast_x_kernel<<<dim3((unsigned)(total / 256)), 256, 0, stream>>>(
        x, xh, xh + total);
  }
  cast_w_kernel<<<dim3(G4_ / 32, FP_ / 32), 256, 0, stream>>>(
      W0, W0t, W0t + (size_t)G4_ * FP_, F_, G4_, FP_);
  cast_w_kernel<<<dim3(G4_ / 32, U_ / 32), 256, 0, stream>>>(
      R0, R0t, R0t + (size_t)G4_ * U_, U_, G4_, U_);
  cast_w_kernel<<<dim3(G4_ / 32, U_ / 32), 256, 0, stream>>>(
      W1, W1t, W1t + (size_t)G4_ * U_, U_, G4_, U_);
  cast_w_kernel<<<dim3(G4_ / 32, U_ / 32), 256, 0, stream>>>(
      R1, R1t, R1t + (size_t)G4_ * U_, U_, G4_, U_);

  dim3 ggrid3(G4_ / 128, B_ / 64, 9);
  dim3 ggrid1(G4_ / 128, B_ / 64, 3);
  const size_t xLoOff = (size_t)T_ * B_ * FP_;
  const size_t hLoOff = (size_t)B_ * U_;

  for (int t = 0; t < T_; t++) {
    const _Float16* xt = xh + (size_t)t * B_ * FP_;
    GemmOp op0 = {xt, W0t, G0x, G0xa, G0xb, FP_, FP_, xLoOff};
    GemmOp op1 = {h0p, R0t, G0h, G0ha, G0hb, U_, U_, hLoOff};
    GemmOp op2 = {h1p, R1t, G1h, G1ha, G1hb, U_, U_, hLoOff};
    // G0x = x_t @ W0 ; G0h = h0 @ R0 ; G1h = h1 @ R1   (9 slices: 3 ops x 3 segs)
    gemm3_kernel<<<ggrid3, 128, 0, stream>>>(op0, op1, op2);
    cell_kernel<<<B_, 256, 0, stream>>>(G0x, G0xa, G0xb, G0h, G0ha, G0hb,
                                        b0, kg0, kb0, rg0, rb0, sg0, sb0,
                                        c0s, h0p, hn0p, (float*)nullptr, mask, t);
    // G1x = hn0 @ W1   (3 slices: 1 op x 3 segs)
    GemmOp opd = {hn0p, W1t, G1x, G1xa, G1xb, U_, U_, hLoOff};
    gemm3_kernel<<<ggrid1, 128, 0, stream>>>(opd, opd, opd);
    cell_kernel<<<B_, 256, 0, stream>>>(G1x, G1xa, G1xb, G1h, G1ha, G1hb,
                                        b1, kg1, kb1, rg1, rb1, sg1, sb1,
                                        c1s, h1p, (_Float16*)nullptr, outf, mask, t);
  }

  dense_softmax_kernel<<<B_, 64, 0, stream>>>(outf, Wd, bd, out);
}

// Round 5
// 5095.869 us; speedup vs baseline: 1.4555x; 1.4555x over previous
//
#include <hip/hip_runtime.h>

#define B_ 1024
#define T_ 100
#define F_ 300
#define FP_ 320
#define U_ 512
#define G4_ 2048
#define C_ 10
#define EPS_ 1e-3f

typedef _Float16 f16x8 __attribute__((ext_vector_type(8)));
typedef float f32x4 __attribute__((ext_vector_type(4)));

typedef __attribute__((address_space(1))) const void* gcptr_t;
typedef __attribute__((address_space(3))) void* lptr_t;

__device__ __forceinline__ void async_ld16(_Float16* lds, const _Float16* g) {
  __builtin_amdgcn_global_load_lds((gcptr_t)g, (lptr_t)lds, 16, 0, 0);
}

// ---------------- prologue kernels ----------------

// x (B,T,F) fp32 -> x_hi/x_lo [T][B][FP_] fp16 split, zero-padded F..FP_
__global__ __launch_bounds__(256) void cast_x_kernel(const float* __restrict__ x,
                                                     _Float16* __restrict__ xhi,
                                                     _Float16* __restrict__ xlo) {
  size_t idx = (size_t)blockIdx.x * 256 + threadIdx.x;
  int f = (int)(idx % FP_);
  size_t bt = idx / FP_;
  int b = (int)(bt % B_);
  int t = (int)(bt / B_);
  float v = 0.f;
  if (f < F_) v = x[((size_t)b * T_ + t) * F_ + f];
  _Float16 h = (_Float16)v;
  xhi[idx] = h;
  xlo[idx] = (_Float16)(v - (float)h);
}

// W [K][N] fp32 -> Wt_hi/Wt_lo [N][Kp] fp16 split (transposed, zero-padded K..Kp)
__global__ __launch_bounds__(256) void cast_w_kernel(const float* __restrict__ W,
                                                     _Float16* __restrict__ Whi,
                                                     _Float16* __restrict__ Wlo,
                                                     int K, int N, int Kp) {
  __shared__ float tile[32][33];
  int n0 = blockIdx.x * 32, k0 = blockIdx.y * 32;
  int tx = threadIdx.x & 31, ty = threadIdx.x >> 5;
#pragma unroll
  for (int r = 0; r < 32; r += 8) {
    int k = k0 + ty + r;
    tile[ty + r][tx] = (k < K) ? W[(size_t)k * N + n0 + tx] : 0.f;
  }
  __syncthreads();
#pragma unroll
  for (int r = 0; r < 32; r += 8) {
    int n = n0 + ty + r, kk = k0 + tx;
    if (kk < Kp) {
      float v = tile[tx][ty + r];
      _Float16 h = (_Float16)v;
      Whi[(size_t)n * Kp + kk] = h;
      Wlo[(size_t)n * Kp + kk] = (_Float16)(v - (float)h);
    }
  }
}

// ---------------- GEMM phase: up to 4 independent ops, one per blockIdx.z ----------
// G = A (MxK) * Bt^T (Bt is [N][K]) -> G [M][2048] fp32.
// Split-fp16 serial 3-segment inside the block: A_hi@B_hi + A_lo@B_hi + A_hi@B_lo.
// Block tile 64(M)x128(N), BK=64, 128 threads = 2 waves, wave tile 64x64.
// Staging: global_load_lds 16B, XOR-swizzled chunk layout (conflict-free b128 reads).
struct GemmOp {
  const _Float16* A;   // hi plane; lo plane at A + aLo
  const _Float16* Bt;  // hi plane; lo plane at Bt + G4_*K
  float* G;
  int lda;
  int K;
  size_t aLo;
};
struct G4Pack {
  GemmOp op[4];
};

__global__ __launch_bounds__(128) void gemm_phase(G4Pack P) {
  GemmOp op = P.op[blockIdx.z];
  const int K = op.K, lda = op.lda;
  const _Float16* A = op.A;
  const _Float16* Bt = op.Bt;

  __shared__ __align__(16) _Float16 as[64][64];   // 8 KB
  __shared__ __align__(16) _Float16 bs[128][64];  // 16 KB

  const int tid = threadIdx.x;
  const int w = tid >> 6;  // 0..1
  const int lane = tid & 63;
  const int mBase = blockIdx.y * 64, nBase = blockIdx.x * 128;
  const int wn = w << 6;

  f32x4 acc[4][4];
#pragma unroll
  for (int mt = 0; mt < 4; mt++)
#pragma unroll
    for (int nt = 0; nt < 4; nt++) acc[mt][nt] = (f32x4){0.f, 0.f, 0.f, 0.f};

  const size_t bLo = (size_t)G4_ * K;
#pragma unroll 1
  for (int s = 0; s < 3; s++) {
    const _Float16* Ap = A + ((s == 1) ? op.aLo : 0);
    const _Float16* Bp = Bt + ((s == 2) ? bLo : 0);
#pragma unroll 1
    for (int k0 = 0; k0 < K; k0 += 64) {
      // stage A: 8 issues total (4 per wave), each 64 lanes x 16B
#pragma unroll
      for (int j = 0; j < 4; j++) {
        int i = (w << 2) + j;
        int idx = (i << 6) + lane;
        int row = idx >> 3;
        int cl = ((idx & 7) ^ (row & 7)) << 3;
        async_ld16(&as[0][0] + (i << 9),
                   Ap + (size_t)(mBase + row) * lda + k0 + cl);
      }
      // stage B: 16 issues total (8 per wave)
#pragma unroll
      for (int j = 0; j < 8; j++) {
        int i = (w << 3) + j;
        int idx = (i << 6) + lane;
        int row = idx >> 3;
        int cl = ((idx & 7) ^ (row & 7)) << 3;
        async_ld16(&bs[0][0] + (i << 9),
                   Bp + (size_t)(nBase + row) * K + k0 + cl);
      }
      __syncthreads();
#pragma unroll
      for (int q = 0; q < 2; q++) {
        f16x8 af[4], bf[4];
#pragma unroll
        for (int mt = 0; mt < 4; mt++) {
          int row = (mt << 4) + (lane & 15);
          int p = ((q << 2) + (lane >> 4)) ^ (row & 7);
          af[mt] = *(const f16x8*)&as[row][p << 3];
        }
#pragma unroll
        for (int nt = 0; nt < 4; nt++) {
          int row = wn + (nt << 4) + (lane & 15);
          int p = ((q << 2) + (lane >> 4)) ^ (row & 7);
          bf[nt] = *(const f16x8*)&bs[row][p << 3];
        }
#pragma unroll
        for (int mt = 0; mt < 4; mt++)
#pragma unroll
          for (int nt = 0; nt < 4; nt++)
            acc[mt][nt] = __builtin_amdgcn_mfma_f32_16x16x32_f16(af[mt], bf[nt], acc[mt][nt], 0, 0, 0);
      }
      __syncthreads();
    }
  }
  // C/D layout: col = lane&15, row = (lane>>4)*4 + reg
  int q = lane >> 4, c = lane & 15;
  float* G = op.G;
#pragma unroll
  for (int mt = 0; mt < 4; mt++)
#pragma unroll
    for (int nt = 0; nt < 4; nt++)
#pragma unroll
      for (int r = 0; r < 4; r++) {
        int row = mBase + (mt << 4) + (q << 2) + r;
        int col = nBase + wn + (nt << 4) + c;
        G[(size_t)row * G4_ + col] = acc[mt][nt][r];
      }
}

// ---------------- cell phase: up to 2 independent cells, blockIdx.x>>10 selects ----

__device__ __forceinline__ void block_reduce(float* v, int n, float* sred, int tid) {
  int lane = tid & 63, w = tid >> 6;
  for (int off = 32; off > 0; off >>= 1)
    for (int i = 0; i < n; i++) v[i] += __shfl_down(v[i], off, 64);
  if (lane == 0)
    for (int i = 0; i < n; i++) sred[w * 4 + i] = v[i];
  __syncthreads();
  if (tid == 0)
    for (int i = 0; i < n; i++) sred[16 + i] = sred[i] + sred[4 + i] + sred[8 + i] + sred[12 + i];
  __syncthreads();
  for (int i = 0; i < n; i++) v[i] = sred[16 + i];
}

__device__ __forceinline__ float sigm(float x) { return 1.f / (1.f + expf(-x)); }

struct CellOp {
  const float* Gx;
  const float* Gh;
  const float* bias;
  const float* kg;
  const float* kb;
  const float* rg;
  const float* rb;
  const float* sg;
  const float* sb;
  float* cS;
  _Float16* hP;   // hi plane; lo at +B_*U_
  _Float16* hnP;  // layer-0 only (else null)
  float* outb;    // layer-1 only (else null)
  int step;
};
struct C2Pack {
  CellOp op[2];
};

__global__ __launch_bounds__(256) void cell_phase(C2Pack P, const int* __restrict__ mask) {
  CellOp cp = P.op[blockIdx.x >> 10];
  int b = blockIdx.x & (B_ - 1);
  int tid = threadIdx.x;
  __shared__ float sred[20];
  const float* gx = cp.Gx + (size_t)b * G4_;
  const float* gh = cp.Gh + (size_t)b * G4_;
  float vx[8], vh[8];
  float s[4] = {0.f, 0.f, 0.f, 0.f};
#pragma unroll
  for (int i = 0; i < 8; i++) {
    int col = tid + (i << 8);
    float a = gx[col], d = gh[col];
    vx[i] = a;
    vh[i] = d;
    s[0] += a;
    s[1] += a * a;
    s[2] += d;
    s[3] += d * d;
  }
  block_reduce(s, 4, sred, tid);
  const float inv = 1.f / 2048.f;
  float m1 = s[0] * inv, m2 = s[2] * inv;
  float rs1 = rsqrtf(fmaxf(s[1] * inv - m1 * m1, 0.f) + EPS_);
  float rs2 = rsqrtf(fmaxf(s[3] * inv - m2 * m2, 0.f) + EPS_);
  float z[8];
#pragma unroll
  for (int i = 0; i < 8; i++) {
    int col = tid + (i << 8);
    z[i] = (vx[i] - m1) * rs1 * cp.kg[col] + cp.kb[col] +
           (vh[i] - m2) * rs2 * cp.rg[col] + cp.rb[col] + cp.bias[col];
  }
  // cols: i=0,1 -> i-gate (j0,j1); 2,3 -> f; 4,5 -> g; 6,7 -> o
  int j0 = tid, j1 = tid + 256;
  size_t base = (size_t)b * U_;
  _Float16* hHi = cp.hP;
  _Float16* hLo = cp.hP + (size_t)B_ * U_;
  float co0 = cp.cS[base + j0], co1 = cp.cS[base + j1];
  float cn0 = sigm(z[2]) * co0 + sigm(z[0]) * tanhf(z[4]);
  float cn1 = sigm(z[3]) * co1 + sigm(z[1]) * tanhf(z[5]);
  float t2[2] = {cn0 + cn1, cn0 * cn0 + cn1 * cn1};
  block_reduce(t2, 2, sred, tid);
  const float invU = 1.f / 512.f;
  float mc = t2[0] * invU;
  float rsc = rsqrtf(fmaxf(t2[1] * invU - mc * mc, 0.f) + EPS_);
  float cl0 = (cn0 - mc) * rsc * cp.sg[j0] + cp.sb[j0];
  float cl1 = (cn1 - mc) * rsc * cp.sg[j1] + cp.sb[j1];
  float hn0 = sigm(z[6]) * tanhf(cl0);
  float hn1 = sigm(z[7]) * tanhf(cl1);
  int mk = mask[(size_t)b * T_ + cp.step];
  float ho0 = (float)hHi[base + j0] + (float)hLo[base + j0];
  float ho1 = (float)hHi[base + j1] + (float)hLo[base + j1];
  float hs0 = mk ? hn0 : ho0, hs1 = mk ? hn1 : ho1;
  _Float16 hh0 = (_Float16)hs0, hh1 = (_Float16)hs1;
  hHi[base + j0] = hh0;
  hLo[base + j0] = (_Float16)(hs0 - (float)hh0);
  hHi[base + j1] = hh1;
  hLo[base + j1] = (_Float16)(hs1 - (float)hh1);
  cp.cS[base + j0] = mk ? cl0 : co0;
  cp.cS[base + j1] = mk ? cl1 : co1;
  if (cp.hnP) {  // layer-0: unmasked h_new feeds layer 1 (reference semantics)
    _Float16* nHi = cp.hnP;
    _Float16* nLo = cp.hnP + (size_t)B_ * U_;
    _Float16 n0 = (_Float16)hn0, n1 = (_Float16)hn1;
    nHi[base + j0] = n0;
    nLo[base + j0] = (_Float16)(hn0 - (float)n0);
    nHi[base + j1] = n1;
    nLo[base + j1] = (_Float16)(hn1 - (float)n1);
  }
  if (cp.outb) {  // layer-1: out = mask ? hn : out_prev
    float oo0 = cp.outb[base + j0], oo1 = cp.outb[base + j1];
    cp.outb[base + j0] = mk ? hn0 : oo0;
    cp.outb[base + j1] = mk ? hn1 : oo1;
  }
}

// ---------------- final dense + softmax ----------------
__global__ __launch_bounds__(64) void dense_softmax_kernel(const float* __restrict__ outb,
                                                           const float* __restrict__ Wd,
                                                           const float* __restrict__ bd,
                                                           float* __restrict__ o) {
  int b = blockIdx.x, lane = threadIdx.x;
  __shared__ float sl[16];
  int col = lane & 15, kg = lane >> 4;
  float acc = 0.f;
  if (col < C_) {
    for (int k = kg; k < U_; k += 4) acc += outb[(size_t)b * U_ + k] * Wd[(size_t)k * C_ + col];
  }
  acc += __shfl_down(acc, 16, 64);
  acc += __shfl_down(acc, 32, 64);
  if (lane < C_) sl[lane] = acc + bd[lane];
  __syncthreads();
  if (lane < C_) {
    float mx = sl[0];
    for (int i = 1; i < C_; i++) mx = fmaxf(mx, sl[i]);
    float ssum = 0.f;
    for (int i = 0; i < C_; i++) ssum += expf(sl[i] - mx);
    o[(size_t)b * C_ + lane] = expf(sl[lane] - mx) / ssum;
  }
}

// ---------------- host ----------------

extern "C" void kernel_launch(void* const* d_in, const int* in_sizes, int n_in,
                              void* d_out, int out_size, void* d_ws, size_t ws_size,
                              hipStream_t stream) {
  const float* x = (const float*)d_in[0];
  const int* mask = (const int*)d_in[1];
  const float* W0 = (const float*)d_in[2];
  const float* R0 = (const float*)d_in[3];
  const float* b0 = (const float*)d_in[4];
  const float* kg0 = (const float*)d_in[5];
  const float* kb0 = (const float*)d_in[6];
  const float* rg0 = (const float*)d_in[7];
  const float* rb0 = (const float*)d_in[8];
  const float* sg0 = (const float*)d_in[9];
  const float* sb0 = (const float*)d_in[10];
  const float* W1 = (const float*)d_in[11];
  const float* R1 = (const float*)d_in[12];
  const float* b1 = (const float*)d_in[13];
  const float* kg1 = (const float*)d_in[14];
  const float* kb1 = (const float*)d_in[15];
  const float* rg1 = (const float*)d_in[16];
  const float* rb1 = (const float*)d_in[17];
  const float* sg1 = (const float*)d_in[18];
  const float* sb1 = (const float*)d_in[19];
  const float* Wd = (const float*)d_in[20];
  const float* bd = (const float*)d_in[21];
  float* out = (float*)d_out;

  char* w = (char*)d_ws;
  size_t o = 0;
  auto alloc = [&](size_t bytes) {
    size_t r = o;
    o += (bytes + 255) & ~(size_t)255;
    return r;
  };
  // zero region (contiguous, first): states + G0h (must be 0 for cell0(0))
  size_t o_c0s = alloc((size_t)B_ * U_ * 4);
  size_t o_c1s = alloc((size_t)B_ * U_ * 4);
  size_t o_outf = alloc((size_t)B_ * U_ * 4);
  size_t o_h0p = alloc((size_t)B_ * U_ * 2 * 2);  // hi + lo contiguous
  size_t o_h1p = alloc((size_t)B_ * U_ * 2 * 2);
  size_t o_G0h = alloc((size_t)B_ * G4_ * 4);
  size_t zero_bytes = o;
  size_t o_hn0p = alloc((size_t)B_ * U_ * 2 * 2);
  size_t o_xh = alloc((size_t)T_ * B_ * FP_ * 2 * 2);  // hi + lo
  size_t o_W0t = alloc((size_t)G4_ * FP_ * 2 * 2);
  size_t o_R0t = alloc((size_t)G4_ * U_ * 2 * 2);
  size_t o_W1t = alloc((size_t)G4_ * U_ * 2 * 2);
  size_t o_R1t = alloc((size_t)G4_ * U_ * 2 * 2);
  size_t o_G0x = alloc((size_t)B_ * G4_ * 4);
  size_t o_G1x = alloc((size_t)B_ * G4_ * 4);
  size_t o_G1h = alloc((size_t)B_ * G4_ * 4);
  (void)ws_size;

  float* c0s = (float*)(w + o_c0s);
  float* c1s = (float*)(w + o_c1s);
  float* outf = (float*)(w + o_outf);
  _Float16* h0p = (_Float16*)(w + o_h0p);
  _Float16* h1p = (_Float16*)(w + o_h1p);
  float* G0h = (float*)(w + o_G0h);
  _Float16* hn0p = (_Float16*)(w + o_hn0p);
  _Float16* xh = (_Float16*)(w + o_xh);
  _Float16* W0t = (_Float16*)(w + o_W0t);
  _Float16* R0t = (_Float16*)(w + o_R0t);
  _Float16* W1t = (_Float16*)(w + o_W1t);
  _Float16* R1t = (_Float16*)(w + o_R1t);
  float* G0x = (float*)(w + o_G0x);
  float* G1x = (float*)(w + o_G1x);
  float* G1h = (float*)(w + o_G1h);

  hipMemsetAsync(w, 0, zero_bytes, stream);

  {
    size_t total = (size_t)T_ * B_ * FP_;
    cast_x_kernel<<<dim3((unsigned)(total / 256)), 256, 0, stream>>>(
        x, xh, xh + total);
  }
  cast_w_kernel<<<dim3(G4_ / 32, FP_ / 32), 256, 0, stream>>>(
      W0, W0t, W0t + (size_t)G4_ * FP_, F_, G4_, FP_);
  cast_w_kernel<<<dim3(G4_ / 32, U_ / 32), 256, 0, stream>>>(
      R0, R0t, R0t + (size_t)G4_ * U_, U_, G4_, U_);
  cast_w_kernel<<<dim3(G4_ / 32, U_ / 32), 256, 0, stream>>>(
      W1, W1t, W1t + (size_t)G4_ * U_, U_, G4_, U_);
  cast_w_kernel<<<dim3(G4_ / 32, U_ / 32), 256, 0, stream>>>(
      R1, R1t, R1t + (size_t)G4_ * U_, U_, G4_, U_);

  const size_t xLoOff = (size_t)T_ * B_ * FP_;
  const size_t hLoOff = (size_t)B_ * U_;

  auto xw_op = [&](int t) -> GemmOp {
    return GemmOp{xh + (size_t)t * B_ * FP_, W0t, G0x, FP_, FP_, xLoOff};
  };
  CellOp cell0op = {G0x, G0h, b0, kg0, kb0, rg0, rb0, sg0, sb0,
                    c0s, h0p, hn0p, nullptr, 0};
  CellOp cell1op = {G1x, G1h, b1, kg1, kb1, rg1, rb1, sg1, sb1,
                    c1s, h1p, nullptr, outf, 0};

  // ---- prime: G0x(0) = x0 @ W0 ; then cell0(0) (G0h is zeroed) ----
  {
    G4Pack P;
    P.op[0] = xw_op(0);
    P.op[1] = P.op[0];
    P.op[2] = P.op[0];
    P.op[3] = P.op[0];
    gemm_phase<<<dim3(G4_ / 128, B_ / 64, 1), 128, 0, stream>>>(P);
    C2Pack CP;
    cell0op.step = 0;
    CP.op[0] = cell0op;
    CP.op[1] = cell0op;
    cell_phase<<<B_, 256, 0, stream>>>(CP, mask);
  }

  // ---- steady loop: A(t) = GEMMs, B(t) = cells ----
  for (int t = 0; t < T_; t++) {
    bool more = (t < T_ - 1);
    G4Pack P;
    P.op[0] = GemmOp{hn0p, W1t, G1x, U_, U_, hLoOff};  // G1x(t) = hn0(t) @ W1
    P.op[1] = GemmOp{h1p, R1t, G1h, U_, U_, hLoOff};   // G1h(t) = h1(t-1) @ R1
    if (more) {
      P.op[2] = GemmOp{h0p, R0t, G0h, U_, U_, hLoOff};  // G0h(t+1) = h0(t) @ R0
      P.op[3] = xw_op(t + 1);                           // G0x(t+1) = x(t+1) @ W0
    } else {
      P.op[2] = P.op[0];
      P.op[3] = P.op[0];
    }
    gemm_phase<<<dim3(G4_ / 128, B_ / 64, more ? 4 : 2), 128, 0, stream>>>(P);

    C2Pack CP;
    cell1op.step = t;
    CP.op[0] = cell1op;
    cell0op.step = t + 1;
    CP.op[1] = more ? cell0op : cell1op;
    cell_phase<<<more ? 2 * B_ : B_, 256, 0, stream>>>(CP, mask);
  }

  dense_softmax_kernel<<<B_, 64, 0, stream>>>(outf, Wd, bd, out);
}

// Round 6
// 4883.415 us; speedup vs baseline: 1.5188x; 1.0435x over previous
//
#include <hip/hip_runtime.h>

#define B_ 1024
#define T_ 100
#define F_ 300
#define FP_ 320
#define U_ 512
#define G4_ 2048
#define C_ 10
#define EPS_ 1e-3f

typedef _Float16 f16x8 __attribute__((ext_vector_type(8)));
typedef float f32x4 __attribute__((ext_vector_type(4)));

typedef __attribute__((address_space(1))) const void* gcptr_t;
typedef __attribute__((address_space(3))) void* lptr_t;

__device__ __forceinline__ void async_ld16(_Float16* lds, const _Float16* g) {
  __builtin_amdgcn_global_load_lds((gcptr_t)g, (lptr_t)lds, 16, 0, 0);
}

// ---------------- prologue kernels ----------------

// x (B,T,F) fp32 -> x_hi/x_lo [T][B][FP_] fp16 split, zero-padded F..FP_
// one thread per 8-element chunk; float4 reads, 16B f16x8 stores.
__global__ __launch_bounds__(256) void cast_x_kernel(const float* __restrict__ x,
                                                     _Float16* __restrict__ xhi,
                                                     _Float16* __restrict__ xlo) {
  size_t cidx = (size_t)blockIdx.x * 256 + threadIdx.x;  // [T*B*FP_/8)
  int fc = (int)(cidx % (FP_ / 8));
  size_t bt = cidx / (FP_ / 8);
  int b = (int)(bt % B_);
  int t = (int)(bt / B_);
  int f = fc * 8;
  const float* xr = x + ((size_t)b * T_ + t) * F_;
  float v[8];
  if (f + 8 <= F_) {
    float4 a = *(const float4*)(xr + f);
    float4 c = *(const float4*)(xr + f + 4);
    v[0] = a.x; v[1] = a.y; v[2] = a.z; v[3] = a.w;
    v[4] = c.x; v[5] = c.y; v[6] = c.z; v[7] = c.w;
  } else {
#pragma unroll
    for (int i = 0; i < 8; i++) v[i] = (f + i < F_) ? xr[f + i] : 0.f;
  }
  f16x8 hi, lo;
#pragma unroll
  for (int i = 0; i < 8; i++) {
    _Float16 h = (_Float16)v[i];
    hi[i] = h;
    lo[i] = (_Float16)(v[i] - (float)h);
  }
  *(f16x8*)(xhi + cidx * 8) = hi;
  *(f16x8*)(xlo + cidx * 8) = lo;
}

// W [K][N] fp32 -> Wt_hi/Wt_lo [N][Kp] fp16 split (transposed, zero-padded K..Kp)
__global__ __launch_bounds__(256) void cast_w_kernel(const float* __restrict__ W,
                                                     _Float16* __restrict__ Whi,
                                                     _Float16* __restrict__ Wlo,
                                                     int K, int N, int Kp) {
  __shared__ float tile[32][33];
  int n0 = blockIdx.x * 32, k0 = blockIdx.y * 32;
  int tx = threadIdx.x & 31, ty = threadIdx.x >> 5;
#pragma unroll
  for (int r = 0; r < 32; r += 8) {
    int k = k0 + ty + r;
    tile[ty + r][tx] = (k < K) ? W[(size_t)k * N + n0 + tx] : 0.f;
  }
  __syncthreads();
#pragma unroll
  for (int r = 0; r < 32; r += 8) {
    int n = n0 + ty + r, kk = k0 + tx;
    if (kk < Kp) {
      float v = tile[tx][ty + r];
      _Float16 h = (_Float16)v;
      Whi[(size_t)n * Kp + kk] = h;
      Wlo[(size_t)n * Kp + kk] = (_Float16)(v - (float)h);
    }
  }
}

// ---------------- GEMM phase: up to 4 independent ops, one per blockIdx.z ----------
// G = A (MxK) * Bt^T (Bt is [N][K]) -> G [M][2048] fp32.
// Split-fp16 serial 3-segment: A_hi@B_hi + A_lo@B_hi + A_hi@B_lo.
// Block tile 128(M)x128(N), BK=64, 256 threads = 4 waves in 2x2, wave tile 64x64.
// Staging: global_load_lds 16B, XOR-swizzled chunk layout (conflict-free b128 reads).
struct GemmOp {
  const _Float16* A;   // hi plane; lo plane at A + aLo
  const _Float16* Bt;  // hi plane; lo plane at Bt + G4_*K
  float* G;
  int lda;
  int K;
  size_t aLo;
};
struct G4Pack {
  GemmOp op[4];
};

__global__ __launch_bounds__(256) void gemm_phase(G4Pack P) {
  GemmOp op = P.op[blockIdx.z];
  const int K = op.K, lda = op.lda;
  const _Float16* A = op.A;
  const _Float16* Bt = op.Bt;

  __shared__ __align__(16) _Float16 as[128][64];  // 16 KB
  __shared__ __align__(16) _Float16 bs[128][64];  // 16 KB

  const int tid = threadIdx.x;
  const int w = tid >> 6;  // 0..3
  const int lane = tid & 63;
  const int mBase = blockIdx.y * 128, nBase = blockIdx.x * 128;
  const int wm = (w & 1) << 6;   // wave row offset in block tile
  const int wn = (w >> 1) << 6;  // wave col offset

  f32x4 acc[4][4];
#pragma unroll
  for (int mt = 0; mt < 4; mt++)
#pragma unroll
    for (int nt = 0; nt < 4; nt++) acc[mt][nt] = (f32x4){0.f, 0.f, 0.f, 0.f};

  const size_t bLo = (size_t)G4_ * K;
#pragma unroll 1
  for (int s = 0; s < 3; s++) {
    const _Float16* Ap = A + ((s == 1) ? op.aLo : 0);
    const _Float16* Bp = Bt + ((s == 2) ? bLo : 0);
#pragma unroll 1
    for (int k0 = 0; k0 < K; k0 += 64) {
      // stage A: 16 issues total (4 per wave), each 64 lanes x 16B; 128 rows x 64 cols
#pragma unroll
      for (int j = 0; j < 4; j++) {
        int i = (w << 2) + j;
        int idx = (i << 6) + lane;
        int row = idx >> 3;
        int cl = ((idx & 7) ^ (row & 7)) << 3;
        async_ld16(&as[0][0] + (i << 9),
                   Ap + (size_t)(mBase + row) * lda + k0 + cl);
      }
      // stage B: 16 issues total (4 per wave)
#pragma unroll
      for (int j = 0; j < 4; j++) {
        int i = (w << 2) + j;
        int idx = (i << 6) + lane;
        int row = idx >> 3;
        int cl = ((idx & 7) ^ (row & 7)) << 3;
        async_ld16(&bs[0][0] + (i << 9),
                   Bp + (size_t)(nBase + row) * K + k0 + cl);
      }
      __syncthreads();
#pragma unroll
      for (int q = 0; q < 2; q++) {
        f16x8 af[4], bf[4];
#pragma unroll
        for (int mt = 0; mt < 4; mt++) {
          int row = wm + (mt << 4) + (lane & 15);
          int p = ((q << 2) + (lane >> 4)) ^ (row & 7);
          af[mt] = *(const f16x8*)&as[row][p << 3];
        }
#pragma unroll
        for (int nt = 0; nt < 4; nt++) {
          int row = wn + (nt << 4) + (lane & 15);
          int p = ((q << 2) + (lane >> 4)) ^ (row & 7);
          bf[nt] = *(const f16x8*)&bs[row][p << 3];
        }
#pragma unroll
        for (int mt = 0; mt < 4; mt++)
#pragma unroll
          for (int nt = 0; nt < 4; nt++)
            acc[mt][nt] = __builtin_amdgcn_mfma_f32_16x16x32_f16(af[mt], bf[nt], acc[mt][nt], 0, 0, 0);
      }
      __syncthreads();
    }
  }
  // C/D layout: col = lane&15, row = (lane>>4)*4 + reg
  int q4 = lane >> 4, c = lane & 15;
  float* G = op.G;
#pragma unroll
  for (int mt = 0; mt < 4; mt++)
#pragma unroll
    for (int nt = 0; nt < 4; nt++)
#pragma unroll
      for (int r = 0; r < 4; r++) {
        int row = mBase + wm + (mt << 4) + (q4 << 2) + r;
        int col = nBase + wn + (nt << 4) + c;
        G[(size_t)row * G4_ + col] = acc[mt][nt][r];
      }
}

// ---------------- cell phase: up to 2 independent cells, blockIdx.x>>10 selects ----

__device__ __forceinline__ void block_reduce(float* v, int n, float* sred, int tid) {
  int lane = tid & 63, w = tid >> 6;
  for (int off = 32; off > 0; off >>= 1)
    for (int i = 0; i < n; i++) v[i] += __shfl_down(v[i], off, 64);
  if (lane == 0)
    for (int i = 0; i < n; i++) sred[w * 4 + i] = v[i];
  __syncthreads();
  if (tid == 0)
    for (int i = 0; i < n; i++) sred[16 + i] = sred[i] + sred[4 + i] + sred[8 + i] + sred[12 + i];
  __syncthreads();
  for (int i = 0; i < n; i++) v[i] = sred[16 + i];
}

__device__ __forceinline__ float sigm(float x) { return 1.f / (1.f + expf(-x)); }

struct CellOp {
  const float* Gx;
  const float* Gh;
  const float* bias;
  const float* kg;
  const float* kb;
  const float* rg;
  const float* rb;
  const float* sg;
  const float* sb;
  float* cS;
  _Float16* hP;   // hi plane; lo at +B_*U_
  _Float16* hnP;  // layer-0 only (else null)
  float* outb;    // layer-1 only (else null)
  int step;
};
struct C2Pack {
  CellOp op[2];
};

__global__ __launch_bounds__(256) void cell_phase(C2Pack P, const int* __restrict__ mask) {
  CellOp cp = P.op[blockIdx.x >> 10];
  int b = blockIdx.x & (B_ - 1);
  int tid = threadIdx.x;
  __shared__ float sred[20];
  const float* gx = cp.Gx + (size_t)b * G4_;
  const float* gh = cp.Gh + (size_t)b * G4_;
  float vx[8], vh[8];
  float s[4] = {0.f, 0.f, 0.f, 0.f};
#pragma unroll
  for (int i = 0; i < 8; i++) {
    int col = tid + (i << 8);
    float a = gx[col], d = gh[col];
    vx[i] = a;
    vh[i] = d;
    s[0] += a;
    s[1] += a * a;
    s[2] += d;
    s[3] += d * d;
  }
  block_reduce(s, 4, sred, tid);
  const float inv = 1.f / 2048.f;
  float m1 = s[0] * inv, m2 = s[2] * inv;
  float rs1 = rsqrtf(fmaxf(s[1] * inv - m1 * m1, 0.f) + EPS_);
  float rs2 = rsqrtf(fmaxf(s[3] * inv - m2 * m2, 0.f) + EPS_);
  float z[8];
#pragma unroll
  for (int i = 0; i < 8; i++) {
    int col = tid + (i << 8);
    z[i] = (vx[i] - m1) * rs1 * cp.kg[col] + cp.kb[col] +
           (vh[i] - m2) * rs2 * cp.rg[col] + cp.rb[col] + cp.bias[col];
  }
  // cols: i=0,1 -> i-gate (j0,j1); 2,3 -> f; 4,5 -> g; 6,7 -> o
  int j0 = tid, j1 = tid + 256;
  size_t base = (size_t)b * U_;
  _Float16* hHi = cp.hP;
  _Float16* hLo = cp.hP + (size_t)B_ * U_;
  float co0 = cp.cS[base + j0], co1 = cp.cS[base + j1];
  float cn0 = sigm(z[2]) * co0 + sigm(z[0]) * tanhf(z[4]);
  float cn1 = sigm(z[3]) * co1 + sigm(z[1]) * tanhf(z[5]);
  float t2[2] = {cn0 + cn1, cn0 * cn0 + cn1 * cn1};
  block_reduce(t2, 2, sred, tid);
  const float invU = 1.f / 512.f;
  float mc = t2[0] * invU;
  float rsc = rsqrtf(fmaxf(t2[1] * invU - mc * mc, 0.f) + EPS_);
  float cl0 = (cn0 - mc) * rsc * cp.sg[j0] + cp.sb[j0];
  float cl1 = (cn1 - mc) * rsc * cp.sg[j1] + cp.sb[j1];
  float hn0 = sigm(z[6]) * tanhf(cl0);
  float hn1 = sigm(z[7]) * tanhf(cl1);
  int mk = mask[(size_t)b * T_ + cp.step];
  float ho0 = (float)hHi[base + j0] + (float)hLo[base + j0];
  float ho1 = (float)hHi[base + j1] + (float)hLo[base + j1];
  float hs0 = mk ? hn0 : ho0, hs1 = mk ? hn1 : ho1;
  _Float16 hh0 = (_Float16)hs0, hh1 = (_Float16)hs1;
  hHi[base + j0] = hh0;
  hLo[base + j0] = (_Float16)(hs0 - (float)hh0);
  hHi[base + j1] = hh1;
  hLo[base + j1] = (_Float16)(hs1 - (float)hh1);
  cp.cS[base + j0] = mk ? cl0 : co0;
  cp.cS[base + j1] = mk ? cl1 : co1;
  if (cp.hnP) {  // layer-0: unmasked h_new feeds layer 1 (reference semantics)
    _Float16* nHi = cp.hnP;
    _Float16* nLo = cp.hnP + (size_t)B_ * U_;
    _Float16 n0 = (_Float16)hn0, n1 = (_Float16)hn1;
    nHi[base + j0] = n0;
    nLo[base + j0] = (_Float16)(hn0 - (float)n0);
    nHi[base + j1] = n1;
    nLo[base + j1] = (_Float16)(hn1 - (float)n1);
  }
  if (cp.outb) {  // layer-1: out = mask ? hn : out_prev
    float oo0 = cp.outb[base + j0], oo1 = cp.outb[base + j1];
    cp.outb[base + j0] = mk ? hn0 : oo0;
    cp.outb[base + j1] = mk ? hn1 : oo1;
  }
}

// ---------------- final dense + softmax ----------------
__global__ __launch_bounds__(64) void dense_softmax_kernel(const float* __restrict__ outb,
                                                           const float* __restrict__ Wd,
                                                           const float* __restrict__ bd,
                                                           float* __restrict__ o) {
  int b = blockIdx.x, lane = threadIdx.x;
  __shared__ float sl[16];
  int col = lane & 15, kg = lane >> 4;
  float acc = 0.f;
  if (col < C_) {
    for (int k = kg; k < U_; k += 4) acc += outb[(size_t)b * U_ + k] * Wd[(size_t)k * C_ + col];
  }
  acc += __shfl_down(acc, 16, 64);
  acc += __shfl_down(acc, 32, 64);
  if (lane < C_) sl[lane] = acc + bd[lane];
  __syncthreads();
  if (lane < C_) {
    float mx = sl[0];
    for (int i = 1; i < C_; i++) mx = fmaxf(mx, sl[i]);
    float ssum = 0.f;
    for (int i = 0; i < C_; i++) ssum += expf(sl[i] - mx);
    o[(size_t)b * C_ + lane] = expf(sl[lane] - mx) / ssum;
  }
}

// ---------------- host ----------------

extern "C" void kernel_launch(void* const* d_in, const int* in_sizes, int n_in,
                              void* d_out, int out_size, void* d_ws, size_t ws_size,
                              hipStream_t stream) {
  const float* x = (const float*)d_in[0];
  const int* mask = (const int*)d_in[1];
  const float* W0 = (const float*)d_in[2];
  const float* R0 = (const float*)d_in[3];
  const float* b0 = (const float*)d_in[4];
  const float* kg0 = (const float*)d_in[5];
  const float* kb0 = (const float*)d_in[6];
  const float* rg0 = (const float*)d_in[7];
  const float* rb0 = (const float*)d_in[8];
  const float* sg0 = (const float*)d_in[9];
  const float* sb0 = (const float*)d_in[10];
  const float* W1 = (const float*)d_in[11];
  const float* R1 = (const float*)d_in[12];
  const float* b1 = (const float*)d_in[13];
  const float* kg1 = (const float*)d_in[14];
  const float* kb1 = (const float*)d_in[15];
  const float* rg1 = (const float*)d_in[16];
  const float* rb1 = (const float*)d_in[17];
  const float* sg1 = (const float*)d_in[18];
  const float* sb1 = (const float*)d_in[19];
  const float* Wd = (const float*)d_in[20];
  const float* bd = (const float*)d_in[21];
  float* out = (float*)d_out;

  char* w = (char*)d_ws;
  size_t o = 0;
  auto alloc = [&](size_t bytes) {
    size_t r = o;
    o += (bytes + 255) & ~(size_t)255;
    return r;
  };
  // zero region (contiguous, first): states + G0h (must be 0 for cell0(0))
  size_t o_c0s = alloc((size_t)B_ * U_ * 4);
  size_t o_c1s = alloc((size_t)B_ * U_ * 4);
  size_t o_outf = alloc((size_t)B_ * U_ * 4);
  size_t o_h0p = alloc((size_t)B_ * U_ * 2 * 2);  // hi + lo contiguous
  size_t o_h1p = alloc((size_t)B_ * U_ * 2 * 2);
  size_t o_G0h = alloc((size_t)B_ * G4_ * 4);
  size_t zero_bytes = o;
  size_t o_hn0p = alloc((size_t)B_ * U_ * 2 * 2);
  size_t o_xh = alloc((size_t)T_ * B_ * FP_ * 2 * 2);  // hi + lo
  size_t o_W0t = alloc((size_t)G4_ * FP_ * 2 * 2);
  size_t o_R0t = alloc((size_t)G4_ * U_ * 2 * 2);
  size_t o_W1t = alloc((size_t)G4_ * U_ * 2 * 2);
  size_t o_R1t = alloc((size_t)G4_ * U_ * 2 * 2);
  size_t o_G0x = alloc((size_t)B_ * G4_ * 4);
  size_t o_G1x = alloc((size_t)B_ * G4_ * 4);
  size_t o_G1h = alloc((size_t)B_ * G4_ * 4);
  (void)ws_size;

  float* c0s = (float*)(w + o_c0s);
  float* c1s = (float*)(w + o_c1s);
  float* outf = (float*)(w + o_outf);
  _Float16* h0p = (_Float16*)(w + o_h0p);
  _Float16* h1p = (_Float16*)(w + o_h1p);
  float* G0h = (float*)(w + o_G0h);
  _Float16* hn0p = (_Float16*)(w + o_hn0p);
  _Float16* xh = (_Float16*)(w + o_xh);
  _Float16* W0t = (_Float16*)(w + o_W0t);
  _Float16* R0t = (_Float16*)(w + o_R0t);
  _Float16* W1t = (_Float16*)(w + o_W1t);
  _Float16* R1t = (_Float16*)(w + o_R1t);
  float* G0x = (float*)(w + o_G0x);
  float* G1x = (float*)(w + o_G1x);
  float* G1h = (float*)(w + o_G1h);

  hipMemsetAsync(w, 0, zero_bytes, stream);

  {
    size_t chunks = (size_t)T_ * B_ * (FP_ / 8);
    cast_x_kernel<<<dim3((unsigned)(chunks / 256)), 256, 0, stream>>>(
        x, xh, xh + (size_t)T_ * B_ * FP_);
  }
  cast_w_kernel<<<dim3(G4_ / 32, FP_ / 32), 256, 0, stream>>>(
      W0, W0t, W0t + (size_t)G4_ * FP_, F_, G4_, FP_);
  cast_w_kernel<<<dim3(G4_ / 32, U_ / 32), 256, 0, stream>>>(
      R0, R0t, R0t + (size_t)G4_ * U_, U_, G4_, U_);
  cast_w_kernel<<<dim3(G4_ / 32, U_ / 32), 256, 0, stream>>>(
      W1, W1t, W1t + (size_t)G4_ * U_, U_, G4_, U_);
  cast_w_kernel<<<dim3(G4_ / 32, U_ / 32), 256, 0, stream>>>(
      R1, R1t, R1t + (size_t)G4_ * U_, U_, G4_, U_);

  const size_t xLoOff = (size_t)T_ * B_ * FP_;
  const size_t hLoOff = (size_t)B_ * U_;

  auto xw_op = [&](int t) -> GemmOp {
    return GemmOp{xh + (size_t)t * B_ * FP_, W0t, G0x, FP_, FP_, xLoOff};
  };
  CellOp cell0op = {G0x, G0h, b0, kg0, kb0, rg0, rb0, sg0, sb0,
                    c0s, h0p, hn0p, nullptr, 0};
  CellOp cell1op = {G1x, G1h, b1, kg1, kb1, rg1, rb1, sg1, sb1,
                    c1s, h1p, nullptr, outf, 0};

  // ---- prime: G0x(0) = x0 @ W0 ; then cell0(0) (G0h is zeroed) ----
  {
    G4Pack P;
    P.op[0] = xw_op(0);
    P.op[1] = P.op[0];
    P.op[2] = P.op[0];
    P.op[3] = P.op[0];
    gemm_phase<<<dim3(G4_ / 128, B_ / 128, 1), 256, 0, stream>>>(P);
    C2Pack CP;
    cell0op.step = 0;
    CP.op[0] = cell0op;
    CP.op[1] = cell0op;
    cell_phase<<<B_, 256, 0, stream>>>(CP, mask);
  }

  // ---- steady loop: A(t) = GEMMs, B(t) = cells ----
  for (int t = 0; t < T_; t++) {
    bool more = (t < T_ - 1);
    G4Pack P;
    P.op[0] = GemmOp{hn0p, W1t, G1x, U_, U_, hLoOff};  // G1x(t) = hn0(t) @ W1
    P.op[1] = GemmOp{h1p, R1t, G1h, U_, U_, hLoOff};   // G1h(t) = h1(t-1) @ R1
    if (more) {
      P.op[2] = GemmOp{h0p, R0t, G0h, U_, U_, hLoOff};  // G0h(t+1) = h0(t) @ R0
      P.op[3] = xw_op(t + 1);                           // G0x(t+1) = x(t+1) @ W0
    } else {
      P.op[2] = P.op[0];
      P.op[3] = P.op[0];
    }
    gemm_phase<<<dim3(G4_ / 128, B_ / 128, more ? 4 : 2), 256, 0, stream>>>(P);

    C2Pack CP;
    cell1op.step = t;
    CP.op[0] = cell1op;
    cell0op.step = t + 1;
    CP.op[1] = more ? cell0op : cell1op;
    cell_phase<<<more ? 2 * B_ : B_, 256, 0, stream>>>(CP, mask);
  }

  dense_softmax_kernel<<<B_, 64, 0, stream>>>(outf, Wd, bd, out);
}